// Round 1
// baseline (176.161 us; speedup 1.0000x reference)
//
#include <hip/hip_runtime.h>
#include <cstdint>
#include <cstddef>

#define B_ 4
#define N_ 4096
#define DIN_ 128
#define DOUT_ 64

typedef __attribute__((ext_vector_type(8))) short short8;
typedef __attribute__((ext_vector_type(4))) float f32x4;
typedef __attribute__((ext_vector_type(4))) unsigned short us4;

__device__ __forceinline__ unsigned short f2bf(float f) {
    union { float f; unsigned int i; } v; v.f = f;
    unsigned int i = v.i;
    return (unsigned short)((i + 0x7FFFu + ((i >> 16) & 1u)) >> 16);
}

// ---------------- projection: x[R,128] @ {Wq,Wk,Wv}[128,64] ----------------
// grid 256 blocks (64 rows each), 192 threads: 16 row-groups x 12 col-groups.
// Outputs: qb,kb bf16 [B*N][64]; vT bf16 [B][64][N]; qsq,ksq f32 [B*N].
__global__ __launch_bounds__(192) void proj_kernel(
    const float* __restrict__ x, const float* __restrict__ Wq,
    const float* __restrict__ Wk, const float* __restrict__ Wv,
    unsigned short* __restrict__ qb, unsigned short* __restrict__ kb,
    unsigned short* __restrict__ vT, float* __restrict__ qsq,
    float* __restrict__ ksq)
{
    const int t = threadIdx.x;
    const int cgrp = t % 12;          // 12 col-groups of 16 cols (proj-aligned)
    const int rgrp = t / 12;          // 16 row-groups of 4 rows
    const int R = blockIdx.x * 64 + rgrp * 4;   // global row in [0, B*N)
    const int c0 = cgrp * 16;
    const int proj = c0 >> 6;         // 0=q 1=k 2=v
    const int col = c0 & 63;
    const float* W = (proj == 0) ? Wq : ((proj == 1) ? Wk : Wv);
    const float* xp = x + (size_t)R * DIN_;

    float acc[4][16];
#pragma unroll
    for (int r = 0; r < 4; ++r)
#pragma unroll
        for (int m = 0; m < 16; ++m) acc[r][m] = 0.f;

    for (int d = 0; d < DIN_; ++d) {
        const float4 w0 = *(const float4*)(W + d * 64 + col);
        const float4 w1 = *(const float4*)(W + d * 64 + col + 4);
        const float4 w2 = *(const float4*)(W + d * 64 + col + 8);
        const float4 w3 = *(const float4*)(W + d * 64 + col + 12);
        const float wv[16] = { w0.x, w0.y, w0.z, w0.w,  w1.x, w1.y, w1.z, w1.w,
                               w2.x, w2.y, w2.z, w2.w,  w3.x, w3.y, w3.z, w3.w };
#pragma unroll
        for (int r = 0; r < 4; ++r) {
            const float xr = xp[r * DIN_ + d];
#pragma unroll
            for (int m = 0; m < 16; ++m)
                acc[r][m] = fmaf(xr, wv[m], acc[r][m]);
        }
    }

    if (proj < 2) {
        unsigned short* dst0 = (proj == 0) ? qb : kb;
#pragma unroll
        for (int r = 0; r < 4; ++r) {
            union { unsigned short us[16]; uint4 u4[2]; } pk;
#pragma unroll
            for (int m = 0; m < 16; ++m) pk.us[m] = f2bf(acc[r][m]);
            uint4* dp = (uint4*)(dst0 + (size_t)(R + r) * 64 + col);
            dp[0] = pk.u4[0];
            dp[1] = pk.u4[1];
        }
        // row squared-norms: reduce across the 4 col-groups of this projection.
        // lanes (rgrp*12 + cgrp) for cgrp base multiple of 4 -> xor-closed sets.
#pragma unroll
        for (int r = 0; r < 4; ++r) {
            float s = 0.f;
#pragma unroll
            for (int m = 0; m < 16; ++m) s = fmaf(acc[r][m], acc[r][m], s);
            s += __shfl_xor(s, 1);
            s += __shfl_xor(s, 2);
            if ((cgrp & 3) == 0) {
                float* sq = (proj == 0) ? qsq : ksq;
                sq[R + r] = s;
            }
        }
    } else {
        // v: store transposed vT[b][e][n]
        const int bb = R >> 12;
        const int n = R & (N_ - 1);
#pragma unroll
        for (int m = 0; m < 16; ++m) {
            us4 val = { f2bf(acc[0][m]), f2bf(acc[1][m]),
                        f2bf(acc[2][m]), f2bf(acc[3][m]) };
            *(us4*)(vT + ((size_t)bb * 64 + (col + m)) * N_ + n) = val;
        }
    }
}

// ---------------- flash attention (no-max online softmax) ----------------
// grid (64, 4) = (q-tile, batch); 256 threads = 4 waves; wave w owns 16 q-rows.
__global__ __launch_bounds__(256) void attn_kernel(
    const unsigned short* __restrict__ qb, const unsigned short* __restrict__ kb,
    const unsigned short* __restrict__ vT, const float* __restrict__ qsq,
    const float* __restrict__ ksq, float* __restrict__ out)
{
    __shared__ __align__(16) char smem[8192 * 3 + 256];
    char* Klds = smem;                  // [64][64] bf16, XOR-swizzled rows
    char* Vlds = smem + 8192;           // [64 e][64 k] bf16, XOR-swizzled rows
    char* Plds = smem + 16384;          // 4 waves x [16][64] bf16, swizzled
    float* ksql = (float*)(smem + 24576);

    const int t = threadIdx.x;
    const int w = t >> 6;
    const int lane = t & 63;
    const int li = lane & 15;
    const int g = lane >> 4;
    const int b = blockIdx.y;
    const int q0 = blockIdx.x * 64;

    char* Pw = Plds + w * 2048;

    // Q A-fragments (row = li, d-slice = g*8 + [0,8) and +32)
    const int qrow = q0 + w * 16 + li;
    const size_t qoff = ((size_t)b * N_ + qrow) * 64;
    const short8 qa0 = *(const short8*)(qb + qoff + g * 8);
    const short8 qa1 = *(const short8*)(qb + qoff + 32 + g * 8);

    float qsqr[4];
#pragma unroll
    for (int r = 0; r < 4; ++r)
        qsqr[r] = qsq[(size_t)b * N_ + q0 + w * 16 + g * 4 + r];

    f32x4 oa[4];
    float lsum[4];
#pragma unroll
    for (int i = 0; i < 4; ++i) {
        oa[i] = (f32x4){0.f, 0.f, 0.f, 0.f};
        lsum[i] = 0.f;
    }

    const unsigned short* kbb = kb + (size_t)b * N_ * 64;
    const unsigned short* vtb = vT + (size_t)b * 64 * N_;
    const float* ksqb = ksq + (size_t)b * N_;

    for (int kt = 0; kt < N_ / 64; ++kt) {
        // ---- stage K tile + Vt tile (8KB each) with row-XOR swizzle ----
#pragma unroll
        for (int m = 0; m < 2; ++m) {
            const int idx = t + 256 * m;            // 0..511 16B-chunks
            const int row = idx >> 3, cc = idx & 7;
            const int lb = (row * 128 + cc * 16) ^ ((row & 7) << 4);
            const uint4 kval = *(const uint4*)(kbb + (size_t)(kt * 64 + row) * 64 + cc * 8);
            *(uint4*)(Klds + lb) = kval;
            const uint4 vval = *(const uint4*)(vtb + (size_t)row * N_ + kt * 64 + cc * 8);
            *(uint4*)(Vlds + lb) = vval;
        }
        if (t < 64) ksql[t] = ksqb[kt * 64 + t];
        __syncthreads();

        // ---- S = Q K^T, then p = exp(sqrt(relu(q2+k2-2s))/8), write P ----
#pragma unroll
        for (int c = 0; c < 4; ++c) {
            const int kr = c * 16 + li;
            const int sw = (kr & 7) << 4;
            const short8 kf0 = *(const short8*)(Klds + ((kr * 128 + g * 16) ^ sw));
            const short8 kf1 = *(const short8*)(Klds + ((kr * 128 + 64 + g * 16) ^ sw));
            f32x4 s = (f32x4){0.f, 0.f, 0.f, 0.f};
            s = __builtin_amdgcn_mfma_f32_16x16x32_bf16(qa0, kf0, s, 0, 0, 0);
            s = __builtin_amdgcn_mfma_f32_16x16x32_bf16(qa1, kf1, s, 0, 0, 0);
            const float ksv = ksql[c * 16 + li];
#pragma unroll
            for (int r = 0; r < 4; ++r) {
                const float d2 = qsqr[r] + ksv - 2.0f * s[r];
                const float dist = sqrtf(fmaxf(d2, 0.0f));
                const float p = __expf(dist * 0.125f);   // scores in [0,~0.8]: no max needed
                lsum[r] += p;
                const int prow = g * 4 + r;
                *(unsigned short*)(Pw + ((prow * 128 + (c * 16 + li) * 2) ^ ((prow & 7) << 4)))
                    = f2bf(p);
            }
        }

        // ---- O += P @ V ----
        const int swp = (li & 7) << 4;
        const short8 pa0 = *(const short8*)(Pw + ((li * 128 + g * 16) ^ swp));
        const short8 pa1 = *(const short8*)(Pw + ((li * 128 + 64 + g * 16) ^ swp));
#pragma unroll
        for (int c2 = 0; c2 < 4; ++c2) {
            const int er = c2 * 16 + li;
            const int swv = (er & 7) << 4;
            const short8 vf0 = *(const short8*)(Vlds + ((er * 128 + g * 16) ^ swv));
            const short8 vf1 = *(const short8*)(Vlds + ((er * 128 + 64 + g * 16) ^ swv));
            oa[c2] = __builtin_amdgcn_mfma_f32_16x16x32_bf16(pa0, vf0, oa[c2], 0, 0, 0);
            oa[c2] = __builtin_amdgcn_mfma_f32_16x16x32_bf16(pa1, vf1, oa[c2], 0, 0, 0);
        }
        __syncthreads();
    }

    // ---- normalize + store ----
    float inv[4];
#pragma unroll
    for (int r = 0; r < 4; ++r) {
        float s = lsum[r];
        s += __shfl_xor(s, 1);
        s += __shfl_xor(s, 2);
        s += __shfl_xor(s, 4);
        s += __shfl_xor(s, 8);
        inv[r] = 1.0f / s;
    }
    float* ob = out + ((size_t)b * N_ + q0 + w * 16) * 64;
#pragma unroll
    for (int c2 = 0; c2 < 4; ++c2)
#pragma unroll
        for (int r = 0; r < 4; ++r)
            ob[(size_t)(g * 4 + r) * 64 + c2 * 16 + li] = oa[c2][r] * inv[r];
}

extern "C" void kernel_launch(void* const* d_in, const int* in_sizes, int n_in,
                              void* d_out, int out_size, void* d_ws, size_t ws_size,
                              hipStream_t stream) {
    (void)in_sizes; (void)n_in; (void)out_size; (void)ws_size;
    const float* x  = (const float*)d_in[0];
    const float* Wq = (const float*)d_in[1];
    const float* Wk = (const float*)d_in[2];
    const float* Wv = (const float*)d_in[3];

    char* ws = (char*)d_ws;
    unsigned short* qb = (unsigned short*)(ws);                               // 2 MB
    unsigned short* kb = (unsigned short*)(ws + (size_t)2 * 1024 * 1024);     // 2 MB
    unsigned short* vT = (unsigned short*)(ws + (size_t)4 * 1024 * 1024);     // 2 MB
    float* qsq = (float*)(ws + (size_t)6 * 1024 * 1024);                      // 64 KB
    float* ksq = (float*)(ws + (size_t)6 * 1024 * 1024 + 65536);              // 64 KB

    hipLaunchKernelGGL(proj_kernel, dim3(256), dim3(192), 0, stream,
                       x, Wq, Wk, Wv, qb, kb, vT, qsq, ksq);
    hipLaunchKernelGGL(attn_kernel, dim3(64, 4), dim3(256), 0, stream,
                       qb, kb, vT, qsq, ksq, (float*)d_out);
}

// Round 2
// 128.835 us; speedup vs baseline: 1.3673x; 1.3673x over previous
//
#include <hip/hip_runtime.h>
#include <cstdint>
#include <cstddef>

#define B_ 4
#define N_ 4096
#define DIN_ 128

typedef __attribute__((ext_vector_type(8))) short short8;
typedef __attribute__((ext_vector_type(4))) float f32x4;

__device__ __forceinline__ unsigned short f2bf(float f) {
    union { float f; unsigned int i; } v; v.f = f;
    unsigned int i = v.i;
    return (unsigned short)((i + 0x7FFFu + ((i >> 16) & 1u)) >> 16);
}

__device__ __forceinline__ float fast_sqrtf(float x) {
#if defined(__has_builtin)
#if __has_builtin(__builtin_amdgcn_sqrtf)
    return __builtin_amdgcn_sqrtf(x);
#else
    return sqrtf(x);
#endif
#else
    return sqrtf(x);
#endif
}

// ---------------- projection: x[R,128] @ {Wq,Wk,Wv}[128,64] ----------------
// grid 1024 blocks (16 rows each), 192 threads: cgrp = t>>4 (12 col-groups of
// 16 cols, 4 per projection), r = t&15 (one row per thread).
// Outputs: qb,kb bf16 [B*N][64]; vT bf16 [B][64][N]; qsq,ksq f32 [B*N].
__global__ __launch_bounds__(192) void proj_kernel(
    const float* __restrict__ x, const float* __restrict__ Wq,
    const float* __restrict__ Wk, const float* __restrict__ Wv,
    unsigned short* __restrict__ qb, unsigned short* __restrict__ kb,
    unsigned short* __restrict__ vT, float* __restrict__ qsq,
    float* __restrict__ ksq)
{
    __shared__ float xl[16 * 132];   // padded rows: bank = 4*(r+d4) -> 2-way max
    const int t = threadIdx.x;
    const int R0 = blockIdx.x * 16;

    // stage x tile [16][128] coalesced
#pragma unroll
    for (int j = 0; j < 4; ++j) {
        const int i = t + 192 * j;
        if (i < 512) {
            const int row = i >> 5, dc = i & 31;
            const float4 v = *(const float4*)(x + (size_t)(R0 + row) * DIN_ + dc * 4);
            *(float4*)(&xl[row * 132 + dc * 4]) = v;
        }
    }
    __syncthreads();

    const int cgrp = t >> 4;          // 0..11
    const int r = t & 15;
    const int proj = cgrp >> 2;       // 0=q 1=k 2=v
    const int col16 = (cgrp & 3) * 16;
    const float* __restrict__ W = (proj == 0) ? Wq : ((proj == 1) ? Wk : Wv);

    float acc[16];
#pragma unroll
    for (int m = 0; m < 16; ++m) acc[m] = 0.f;

    for (int d4 = 0; d4 < 32; ++d4) {
        const float4 xv = *(const float4*)(&xl[r * 132 + d4 * 4]);
        const float xs4[4] = { xv.x, xv.y, xv.z, xv.w };
#pragma unroll
        for (int dd = 0; dd < 4; ++dd) {
            const int d = d4 * 4 + dd;
            const float xs = xs4[dd];
            const float4 w0 = *(const float4*)(W + d * 64 + col16);
            const float4 w1 = *(const float4*)(W + d * 64 + col16 + 4);
            const float4 w2 = *(const float4*)(W + d * 64 + col16 + 8);
            const float4 w3 = *(const float4*)(W + d * 64 + col16 + 12);
            acc[0]  = fmaf(xs, w0.x, acc[0]);  acc[1]  = fmaf(xs, w0.y, acc[1]);
            acc[2]  = fmaf(xs, w0.z, acc[2]);  acc[3]  = fmaf(xs, w0.w, acc[3]);
            acc[4]  = fmaf(xs, w1.x, acc[4]);  acc[5]  = fmaf(xs, w1.y, acc[5]);
            acc[6]  = fmaf(xs, w1.z, acc[6]);  acc[7]  = fmaf(xs, w1.w, acc[7]);
            acc[8]  = fmaf(xs, w2.x, acc[8]);  acc[9]  = fmaf(xs, w2.y, acc[9]);
            acc[10] = fmaf(xs, w2.z, acc[10]); acc[11] = fmaf(xs, w2.w, acc[11]);
            acc[12] = fmaf(xs, w3.x, acc[12]); acc[13] = fmaf(xs, w3.y, acc[13]);
            acc[14] = fmaf(xs, w3.z, acc[14]); acc[15] = fmaf(xs, w3.w, acc[15]);
        }
    }

    const int R = R0 + r;
    if (proj < 2) {
        unsigned short* dst0 = (proj == 0) ? qb : kb;
        union { unsigned short us[16]; uint4 u4[2]; } pk;
#pragma unroll
        for (int m = 0; m < 16; ++m) pk.us[m] = f2bf(acc[m]);
        uint4* dp = (uint4*)(dst0 + (size_t)R * 64 + col16);
        dp[0] = pk.u4[0];
        dp[1] = pk.u4[1];
        // row squared-norm: reduce across 4 col-groups (lanes r, r+16, r+32, r+48)
        float s = 0.f;
#pragma unroll
        for (int m = 0; m < 16; ++m) s = fmaf(acc[m], acc[m], s);
        s += __shfl_xor(s, 16);
        s += __shfl_xor(s, 32);
        if ((cgrp & 3) == 0) {
            float* sq = (proj == 0) ? qsq : ksq;
            sq[R] = s;
        }
    } else {
        // v: store transposed vT[b][e][n]
        const int bb = R >> 12;
        const int n = R & (N_ - 1);
#pragma unroll
        for (int m = 0; m < 16; ++m)
            vT[((size_t)bb * 64 + (col16 + m)) * N_ + n] = f2bf(acc[m]);
    }
}

// ---------------- split-K flash attention (no-max online softmax) ----------
// grid (32 q-tiles, 4 batch, S splits); 256 threads = 4 waves; wave owns 32
// q-rows (two 16-row halves h). Writes unnormalized Opart + row-sum Lpart.
__global__ __launch_bounds__(256, 4) void attn_kernel(
    const unsigned short* __restrict__ qb, const unsigned short* __restrict__ kb,
    const unsigned short* __restrict__ vT, const float* __restrict__ qsq,
    const float* __restrict__ ksq, float* __restrict__ Opart,
    float* __restrict__ Lpart, int ktn)
{
    __shared__ __align__(16) char smem[8192 * 2 + 16384 + 256];
    char* Klds = smem;                  // [64 k][64 d] bf16, XOR-swizzled rows
    char* Vlds = smem + 8192;           // [64 e][64 k] bf16, XOR-swizzled rows
    char* Plds = smem + 16384;          // 4 waves x [32][64] bf16, swizzled
    float* ksql = (float*)(smem + 32768);

    const int t = threadIdx.x;
    const int w = t >> 6;
    const int lane = t & 63;
    const int li = lane & 15;
    const int g = lane >> 4;
    const int b = blockIdx.y;
    const int sp = blockIdx.z;
    const int q0 = blockIdx.x * 128;
    const int kt0 = sp * ktn;

    char* Pw = Plds + w * 4096;

    // Q A-fragments for both 16-row halves
    const size_t qbase = ((size_t)b * N_ + q0 + w * 32) * 64;
    short8 qa[2][2];
    float qsqr[2][4];
#pragma unroll
    for (int h = 0; h < 2; ++h) {
        qa[h][0] = *(const short8*)(qb + qbase + (size_t)(h * 16 + li) * 64 + g * 8);
        qa[h][1] = *(const short8*)(qb + qbase + (size_t)(h * 16 + li) * 64 + 32 + g * 8);
#pragma unroll
        for (int r = 0; r < 4; ++r)
            qsqr[h][r] = qsq[(size_t)b * N_ + q0 + w * 32 + h * 16 + g * 4 + r];
    }

    f32x4 oa[2][4];
    float lsum[2][4];
#pragma unroll
    for (int h = 0; h < 2; ++h)
#pragma unroll
        for (int i = 0; i < 4; ++i) {
            oa[h][i] = (f32x4){0.f, 0.f, 0.f, 0.f};
            lsum[h][i] = 0.f;
        }

    const unsigned short* kbb = kb + (size_t)b * N_ * 64;
    const unsigned short* vtb = vT + (size_t)b * 64 * N_;
    const float* ksqb = ksq + (size_t)b * N_;

    for (int ktl = 0; ktl < ktn; ++ktl) {
        const int kt = kt0 + ktl;
        // ---- stage K tile + Vt tile (8KB each), row-XOR swizzle ----
#pragma unroll
        for (int m = 0; m < 2; ++m) {
            const int idx = t + 256 * m;            // 0..511 16B-chunks
            const int row = idx >> 3, cc = idx & 7;
            const int lb = (row * 128 + cc * 16) ^ ((row & 7) << 4);
            *(uint4*)(Klds + lb) = *(const uint4*)(kbb + (size_t)(kt * 64 + row) * 64 + cc * 8);
            *(uint4*)(Vlds + lb) = *(const uint4*)(vtb + (size_t)row * N_ + kt * 64 + cc * 8);
        }
        if (t < 64) ksql[t] = ksqb[kt * 64 + t];
        __syncthreads();

        // ---- S = Q K^T, p = exp(sqrt(relu(q2+k2-2s))/8), write P ----
#pragma unroll
        for (int c = 0; c < 4; ++c) {
            const int kr = c * 16 + li;
            const int sw = (kr & 7) << 4;
            const short8 kf0 = *(const short8*)(Klds + ((kr * 128 + g * 16) ^ sw));
            const short8 kf1 = *(const short8*)(Klds + ((kr * 128 + 64 + g * 16) ^ sw));
            const float ksv = ksql[kr];
#pragma unroll
            for (int h = 0; h < 2; ++h) {
                f32x4 s = (f32x4){0.f, 0.f, 0.f, 0.f};
                s = __builtin_amdgcn_mfma_f32_16x16x32_bf16(qa[h][0], kf0, s, 0, 0, 0);
                s = __builtin_amdgcn_mfma_f32_16x16x32_bf16(qa[h][1], kf1, s, 0, 0, 0);
#pragma unroll
                for (int r = 0; r < 4; ++r) {
                    const float d2 = fmaf(-2.0f, s[r], qsqr[h][r] + ksv);
                    const float dist = fast_sqrtf(fmaxf(d2, 0.0f));
                    const float p = __expf(dist * 0.125f);  // scores in [0,~1]: no max needed
                    lsum[h][r] += p;
                    const int prow = h * 16 + g * 4 + r;
                    *(unsigned short*)(Pw + ((prow * 128 + kr * 2) ^ ((prow & 7) << 4))) = f2bf(p);
                }
            }
        }

        // ---- O += P @ V (V frags shared across both halves) ----
        short8 pa[2][2];
#pragma unroll
        for (int h = 0; h < 2; ++h) {
            const int pr = h * 16 + li;
            const int swp = (pr & 7) << 4;
            pa[h][0] = *(const short8*)(Pw + ((pr * 128 + g * 16) ^ swp));
            pa[h][1] = *(const short8*)(Pw + ((pr * 128 + 64 + g * 16) ^ swp));
        }
#pragma unroll
        for (int c2 = 0; c2 < 4; ++c2) {
            const int er = c2 * 16 + li;
            const int swv = (er & 7) << 4;
            const short8 vf0 = *(const short8*)(Vlds + ((er * 128 + g * 16) ^ swv));
            const short8 vf1 = *(const short8*)(Vlds + ((er * 128 + 64 + g * 16) ^ swv));
#pragma unroll
            for (int h = 0; h < 2; ++h) {
                oa[h][c2] = __builtin_amdgcn_mfma_f32_16x16x32_bf16(pa[h][0], vf0, oa[h][c2], 0, 0, 0);
                oa[h][c2] = __builtin_amdgcn_mfma_f32_16x16x32_bf16(pa[h][1], vf1, oa[h][c2], 0, 0, 0);
            }
        }
        __syncthreads();
    }

    // ---- write partials (unnormalized) ----
    const size_t obase = ((size_t)sp * B_ + b) * N_;
#pragma unroll
    for (int h = 0; h < 2; ++h)
#pragma unroll
        for (int r = 0; r < 4; ++r) {
            float srow = lsum[h][r];
            srow += __shfl_xor(srow, 1);
            srow += __shfl_xor(srow, 2);
            srow += __shfl_xor(srow, 4);
            srow += __shfl_xor(srow, 8);
            const int row = q0 + w * 32 + h * 16 + g * 4 + r;
            if (li == 0) Lpart[obase + row] = srow;
#pragma unroll
            for (int c2 = 0; c2 < 4; ++c2)
                Opart[(obase + row) * 64 + c2 * 16 + li] = oa[h][c2][r];
        }
}

// ---------------- combine splits + normalize ----------------
__global__ __launch_bounds__(256) void reduce_kernel(
    const float* __restrict__ Opart, const float* __restrict__ Lpart,
    float* __restrict__ out, int S)
{
    const int idx = blockIdx.x * 256 + threadIdx.x;   // 262144 threads
    const int rowg = idx >> 4;                        // 0..16383 (b*N+row)
    const int e4 = (idx & 15) << 2;
    float l = 0.f;
    float4 o = {0.f, 0.f, 0.f, 0.f};
    for (int s = 0; s < S; ++s) {
        l += Lpart[(size_t)s * (B_ * N_) + rowg];
        const float4 v = *(const float4*)(Opart + ((size_t)s * (B_ * N_) + rowg) * 64 + e4);
        o.x += v.x; o.y += v.y; o.z += v.z; o.w += v.w;
    }
    const float inv = 1.0f / l;
    const float4 res = {o.x * inv, o.y * inv, o.z * inv, o.w * inv};
    *(float4*)(out + (size_t)rowg * 64 + e4) = res;
}

extern "C" void kernel_launch(void* const* d_in, const int* in_sizes, int n_in,
                              void* d_out, int out_size, void* d_ws, size_t ws_size,
                              hipStream_t stream) {
    (void)in_sizes; (void)n_in; (void)out_size;
    const float* x  = (const float*)d_in[0];
    const float* Wq = (const float*)d_in[1];
    const float* Wk = (const float*)d_in[2];
    const float* Wv = (const float*)d_in[3];

    char* ws = (char*)d_ws;
    const size_t MB = 1024 * 1024;
    unsigned short* qb = (unsigned short*)(ws);                 // 2 MB
    unsigned short* kb = (unsigned short*)(ws + 2 * MB);        // 2 MB
    unsigned short* vT = (unsigned short*)(ws + 4 * MB);        // 2 MB
    float* qsq = (float*)(ws + 6 * MB);                         // 64 KB
    float* ksq = (float*)(ws + 6 * MB + 65536);                 // 64 KB
    float* Lpart = (float*)(ws + 6 * MB + 262144);              // <= 512 KB

    int S;
    float* Opart;
    if (ws_size >= 7 * MB + 32 * MB)      { S = 8; Opart = (float*)(ws + 7 * MB); }
    else if (ws_size >= 7 * MB + 16 * MB) { S = 4; Opart = (float*)(ws + 7 * MB); }
    else if (ws_size >= 7 * MB + 8 * MB)  { S = 2; Opart = (float*)(ws + 7 * MB); }
    else if (ws_size >= 7 * MB + 4 * MB)  { S = 1; Opart = (float*)(ws + 7 * MB); }
    else                                  { S = 1; Opart = (float*)d_out; }

    hipLaunchKernelGGL(proj_kernel, dim3(1024), dim3(192), 0, stream,
                       x, Wq, Wk, Wv, qb, kb, vT, qsq, ksq);
    hipLaunchKernelGGL(attn_kernel, dim3(32, B_, S), dim3(256), 0, stream,
                       qb, kb, vT, qsq, ksq, Opart, Lpart, 64 / S);
    hipLaunchKernelGGL(reduce_kernel, dim3(1024), dim3(256), 0, stream,
                       Opart, Lpart, (float*)d_out, S);
}